// Round 10
// baseline (412.138 us; speedup 1.0000x reference)
//
#include <hip/hip_runtime.h>
#include <hip/hip_bf16.h>

#define IN_DIM  128
#define HID_DIM 128
#define OUT_DIM 64
#define NBUK 1024           // histogram bins (bucket = dst >> 7); buckets >= ceil(N/128) empty
#define NB1  256            // blocks in hist/scatter passes

typedef unsigned short ushort_t;
struct ushort4_t { ushort_t x, y, z, w; };
typedef __attribute__((ext_vector_type(8))) short bf16x8;   // 8 bf16 (4 VGPRs)
typedef __attribute__((ext_vector_type(4))) float f32x4;    // MFMA acc

__device__ __forceinline__ float bf2f(ushort_t u) {
    return __uint_as_float(((unsigned int)u) << 16);
}
__device__ __forceinline__ short f2bf_s(float v) {
    __hip_bfloat16 t = __float2bfloat16(v);
    return *(short*)&t;
}
__device__ __forceinline__ unsigned int pack2(float a, float b) {
    return ((unsigned int)(ushort_t)f2bf_s(b) << 16) | (ushort_t)f2bf_s(a);
}

// ---------------- GEMM1 (MFMA): h1[N,128](bf16) = x[N,128] @ W1[128,128], standalone ----------------
__global__ __launch_bounds__(256, 2) void gemm1_mfma(
        const float* __restrict__ x, const float* __restrict__ W,
        unsigned int* __restrict__ h, int N, int NT, int NW) {
    const int tid  = threadIdx.x;
    const int lane = tid & 63;
    const int m    = lane & 15;
    const int quad = lane >> 4;
    const int gw   = blockIdx.x * 4 + (tid >> 6);

    bf16x8 a[8][4];                         // 8 col-tiles x 4 k-chunks
    #pragma unroll
    for (int ct = 0; ct < 8; ++ct)
        #pragma unroll
        for (int kc = 0; kc < 4; ++kc)
            #pragma unroll
            for (int j = 0; j < 8; ++j)
                a[ct][kc][j] = f2bf_s(W[(size_t)(kc * 32 + quad * 8 + j) * HID_DIM + ct * 16 + m]);

    for (int t = gw; t < NT; t += NW) {
        const int n0 = t * 16;
        int node = n0 + m; if (node >= N) node = N - 1;
        const float* xr = x + (size_t)node * IN_DIM + quad * 8;
        f32x4 acc[8];
        #pragma unroll
        for (int ct = 0; ct < 8; ++ct) acc[ct] = (f32x4){0.f, 0.f, 0.f, 0.f};
        #pragma unroll
        for (int kc = 0; kc < 4; ++kc) {
            const float4 v0 = *(const float4*)(xr + kc * 32);
            const float4 v1 = *(const float4*)(xr + kc * 32 + 4);
            bf16x8 b;
            b[0] = f2bf_s(v0.x); b[1] = f2bf_s(v0.y); b[2] = f2bf_s(v0.z); b[3] = f2bf_s(v0.w);
            b[4] = f2bf_s(v1.x); b[5] = f2bf_s(v1.y); b[6] = f2bf_s(v1.z); b[7] = f2bf_s(v1.w);
            #pragma unroll
            for (int ct = 0; ct < 8; ++ct)
                acc[ct] = __builtin_amdgcn_mfma_f32_16x16x32_bf16(a[ct][kc], b, acc[ct], 0, 0, 0);
        }
        if (n0 + m < N) {
            unsigned int* o = h + (size_t)(n0 + m) * (HID_DIM / 2) + quad * 2;
            #pragma unroll
            for (int ct = 0; ct < 8; ++ct) {
                uint2 pv;
                pv.x = pack2(acc[ct][0], acc[ct][1]);
                pv.y = pack2(acc[ct][2], acc[ct][3]);
                *(uint2*)(o + ct * 8) = pv;
            }
        }
    }
}

// ---------------- K1: per-block bucket histogram (LDS atomics, no global atomics) ----------------
__global__ void bucket_hist(const int* __restrict__ dst, int E, int CH, int* __restrict__ mat) {
    __shared__ int hist[NBUK];
    const int t = threadIdx.x;
    for (int i = t; i < NBUK; i += 256) hist[i] = 0;
    __syncthreads();
    const int lo = blockIdx.x * CH;
    const int hi = min(lo + CH, E);
    for (int e = lo + t; e < hi; e += 256)
        atomicAdd(&hist[dst[e] >> 7], 1);
    __syncthreads();
    for (int i = t; i < NBUK; i += 256) mat[blockIdx.x * NBUK + i] = hist[i];
}

// ---------------- K2: scan (block,bucket) matrix -> start offsets; bucket bases/counts ----------------
__global__ void mat_scan(int* __restrict__ mat, int* __restrict__ bbase, int* __restrict__ bcnt) {
    __shared__ int lsum[NBUK];
    __shared__ int wsum[16];
    const int t = threadIdx.x;              // 1024 threads, one per bucket
    int run = 0;
    for (int b = 0; b < NB1; ++b) {         // column-exclusive scan (coalesced: stride NBUK)
        const int idx = b * NBUK + t;
        const int v = mat[idx];
        mat[idx] = run;
        run += v;
    }
    lsum[t] = run;                          // column sum = bucket edge count
    __syncthreads();
    const int lane = t & 63, w = t >> 6;
    int incl = lsum[t];
    #pragma unroll
    for (int off = 1; off < 64; off <<= 1) {
        int u = __shfl_up(incl, off);
        if (lane >= off) incl += u;
    }
    if (lane == 63) wsum[w] = incl;
    __syncthreads();
    int woff = 0;
    for (int i = 0; i < w; ++i) woff += wsum[i];
    const int excl = woff + incl - lsum[t]; // exclusive bucket base
    bbase[t] = excl;
    bcnt[t]  = lsum[t];
    if (t == NBUK - 1) bbase[NBUK] = excl + lsum[t];
    __syncthreads();
    for (int b = 0; b < NB1; ++b) mat[b * NBUK + t] += excl;
}

// ---------------- K3: scatter edges to bucket-grouped ebuf {src,dst} (coalesced-run writes) ----------------
__global__ void bucket_scatter(const int* __restrict__ src, const int* __restrict__ dst,
                               int E, int CH, const int* __restrict__ mat, int2* __restrict__ ebuf) {
    __shared__ int lofs[NBUK];
    const int t = threadIdx.x;
    for (int i = t; i < NBUK; i += 256) lofs[i] = mat[blockIdx.x * NBUK + i];
    __syncthreads();
    const int lo = blockIdx.x * CH;
    const int hi = min(lo + CH, E);
    for (int e = lo + t; e < hi; e += 256) {
        const int d = dst[e];
        const int pos = atomicAdd(&lofs[d >> 7], 1);    // LDS atomic -> unique slot
        int2 sd; sd.x = src[e]; sd.y = d;
        ebuf[pos] = sd;
    }
}

// ---------------- K4: per-bucket node counts (LDS) -> cnt (coalesced write) ----------------
__global__ void bucket_count(const int2* __restrict__ ebuf, const int* __restrict__ bbase,
                             const int* __restrict__ bcnt, int* __restrict__ cnt, int N) {
    __shared__ int lcnt[128];
    const int t = threadIdx.x;
    if (t < 128) lcnt[t] = 0;
    __syncthreads();
    const int b = blockIdx.x;
    const int base = bbase[b], n = bcnt[b];
    for (int e = t; e < n; e += 256)
        atomicAdd(&lcnt[ebuf[base + e].y & 127], 1);
    __syncthreads();
    const int node0 = b << 7;
    if (t < 128 && node0 + t < N) cnt[node0 + t] = lcnt[t];
}

// ---------------- scan_fused: dinv + row_start (record units, x4), ONE launch (verified r9) ----------------
__global__ void scan_fused(const int* __restrict__ cnt, float* __restrict__ dinv,
                           int* __restrict__ row_start, int N) {
    __shared__ int wsum[4];
    __shared__ int sh_off;
    const int t = threadIdx.x;
    const int base0 = blockIdx.x * 2048;

    int pre = 0;
    for (int i = t * 4; i < base0; i += 1024) {
        const int4 c4 = *(const int4*)(cnt + i);
        pre += ((c4.x + 3) & ~3) + ((c4.y + 3) & ~3) + ((c4.z + 3) & ~3) + ((c4.w + 3) & ~3);
    }
    #pragma unroll
    for (int off = 32; off > 0; off >>= 1) pre += __shfl_down(pre, off);
    const int lane = t & 63, w = t >> 6;
    if (lane == 0) wsum[w] = pre;
    __syncthreads();
    if (t == 0) sh_off = wsum[0] + wsum[1] + wsum[2] + wsum[3];
    __syncthreads();

    const int base = base0 + t * 8;
    int c[8], v[8];
    #pragma unroll
    for (int i = 0; i < 8; ++i) {
        c[i] = (base + i < N) ? cnt[base + i] : 0;
        v[i] = (c[i] + 3) & ~3;
        if (base + i < N) dinv[base + i] = rsqrtf((float)(c[i] + 1));   // +1 self loop
    }
    int s = v[0] + v[1] + v[2] + v[3] + v[4] + v[5] + v[6] + v[7];
    int incl = s;
    #pragma unroll
    for (int off = 1; off < 64; off <<= 1) {
        int u = __shfl_up(incl, off);
        if (lane >= off) incl += u;
    }
    if (lane == 63) wsum[w] = incl;
    __syncthreads();
    int woff = 0;
    for (int i = 0; i < w; ++i) woff += wsum[i];
    int run = sh_off + woff + (incl - s);
    #pragma unroll
    for (int i = 0; i < 8; ++i) {
        if (base + i < N) {
            row_start[base + i] = run;
            run += v[i];
        }
    }
}

// ---------------- K6: per-bucket record build in LDS, flushed coalesced (int4) ----------------
// Bucket's pack region [row_start[node0], regionEnd) is contiguous; pads {0,0} written here.
#define REGCAP 3072     // int2 records = 24KB; bucket edges ~Poisson(1562), cap = +28 sigma
__global__ void bucket_build(const int2* __restrict__ ebuf, const int* __restrict__ bbase,
                             const int* __restrict__ bcnt, const int* __restrict__ row_start,
                             const int* __restrict__ cnt, const float* __restrict__ dinv,
                             int N, int2* __restrict__ pack) {
    __shared__ __align__(16) int2 reg[REGCAP];
    __shared__ int lofs[128];
    __shared__ int lrank[128];
    __shared__ float dv[128];
    __shared__ int s_regLen;
    const int t = threadIdx.x;
    const int b = blockIdx.x;
    const int node0 = b << 7;
    const int nn = min(128, N - node0);
    if (t < nn) {
        lofs[t]  = row_start[node0 + t];
        lrank[t] = 0;
        dv[t]    = dinv[node0 + t];
    }
    __syncthreads();
    const int base = lofs[0];
    if (t == 0) {
        const int lastc = cnt[node0 + nn - 1];
        s_regLen = (lofs[nn - 1] - base) + ((lastc + 3) & ~3);
    }
    __syncthreads();
    const int regLen = s_regLen;
    if (t < nn) lofs[t] -= base;            // region-local offsets
    __syncthreads();

    const int ebase = bbase[b], en = bcnt[b];
    if (regLen <= REGCAP) {
        for (int e = t; e < en; e += 256) {
            const int2 sd = ebuf[ebase + e];
            const int i = sd.y & 127;
            const int r = atomicAdd(&lrank[i], 1);
            int2 p; p.x = sd.x;
            p.y = __float_as_int(dinv[sd.x] * dv[i]);
            reg[lofs[i] + r] = p;
        }
        __syncthreads();
        for (int i = t; i < nn; i += 256) {             // pads: src=0, norm=0
            const int c = lrank[i];
            const int v = (c + 3) & ~3;
            for (int p = c; p < v; ++p) reg[lofs[i] + p] = (int2){0, 0};
        }
        __syncthreads();
        const int n4 = regLen >> 1;                     // regLen multiple of 4 -> int4 pairs
        const int4* s4 = (const int4*)reg;
        int4* d4 = (int4*)(pack + base);                // base multiple of 4 records: 32B aligned
        for (int k = t; k < n4; k += 256) d4[k] = s4[k];
    } else {
        // statistically unreachable fallback: direct global writes
        for (int e = t; e < en; e += 256) {
            const int2 sd = ebuf[ebase + e];
            const int i = sd.y & 127;
            const int r = atomicAdd(&lrank[i], 1);
            int2 p; p.x = sd.x;
            p.y = __float_as_int(dinv[sd.x] * dv[i]);
            pack[base + lofs[i] + r] = p;
        }
        __syncthreads();
        for (int i = t; i < nn; i += 256) {
            const int c = lrank[i];
            const int v = (c + 3) & ~3;
            for (int p = c; p < v; ++p) pack[base + lofs[i] + p] = (int2){0, 0};
        }
    }
}

// ---------------- GEMM2 (MFMA): h2[N,64](bf16) = agg_relu[N,128](bf16) @ W2[128,64] ----------------
__global__ __launch_bounds__(256) void gemm2_mfma(
        const ushort_t* __restrict__ agg,
        const float* __restrict__ W2, unsigned int* __restrict__ h2,
        int N, int NT, int NW) {
    const int tid  = threadIdx.x;
    const int lane = tid & 63;
    const int m    = lane & 15;
    const int quad = lane >> 4;
    const int gw   = blockIdx.x * 4 + (tid >> 6);

    bf16x8 a[4][4];                         // 4 col-tiles x 4 k-chunks
    #pragma unroll
    for (int ct = 0; ct < 4; ++ct)
        #pragma unroll
        for (int kc = 0; kc < 4; ++kc)
            #pragma unroll
            for (int j = 0; j < 8; ++j)
                a[ct][kc][j] = f2bf_s(W2[(size_t)(kc * 32 + quad * 8 + j) * OUT_DIM + ct * 16 + m]);

    for (int t = gw; t < NT; t += NW) {
        const int n0 = t * 16;
        int node = n0 + m; if (node >= N) node = N - 1;
        const ushort_t* ar = agg + (size_t)node * HID_DIM + quad * 8;
        f32x4 acc[4];
        #pragma unroll
        for (int ct = 0; ct < 4; ++ct) acc[ct] = (f32x4){0.f, 0.f, 0.f, 0.f};
        #pragma unroll
        for (int kc = 0; kc < 4; ++kc) {
            const bf16x8 b = *(const bf16x8*)(ar + kc * 32);
            #pragma unroll
            for (int ct = 0; ct < 4; ++ct)
                acc[ct] = __builtin_amdgcn_mfma_f32_16x16x32_bf16(a[ct][kc], b, acc[ct], 0, 0, 0);
        }
        if (n0 + m < N) {
            unsigned int* o = h2 + (size_t)(n0 + m) * (OUT_DIM / 2) + quad * 2;
            #pragma unroll
            for (int ct = 0; ct < 4; ++ct) {
                uint2 pv;
                pv.x = pack2(acc[ct][0], acc[ct][1]);
                pv.y = pack2(acc[ct][2], acc[ct][3]);
                *(uint2*)(o + ct * 8) = pv;
            }
        }
    }
}

// ---------------- gather aggregation over {src, norm} records (round-4 verified form) ----------------
// pad records are {0, 0.0f} -> contribute nothing. bias pre-added (commutes), relu post-loop.
template<int D, bool BF16_OUT, bool RELU>
__global__ void gather_bf16(const ushort_t* __restrict__ h, const int2* __restrict__ pack,
                            const int* __restrict__ row_start, const int* __restrict__ cnt,
                            const float* __restrict__ dinv, const float* __restrict__ bias,
                            int N, void* __restrict__ outv) {
    const int TPN = D / 4;
    const int NPB = 256 / TPN;
    const int t = threadIdx.x;
    const int node = blockIdx.x * NPB + t / TPN;
    if (node >= N) return;
    const int f = (t & (TPN - 1)) * 4;
    const float dd = dinv[node];

    const ushort4_t self = *(const ushort4_t*)(h + (size_t)node * D + f);
    const float sn = dd * dd;
    float4 acc;
    acc.x = bf2f(self.x) * sn; acc.y = bf2f(self.y) * sn;
    acc.z = bf2f(self.z) * sn; acc.w = bf2f(self.w) * sn;
    const float4 bv = *(const float4*)(bias + f);
    acc.x += bv.x; acc.y += bv.y; acc.z += bv.z; acc.w += bv.w;

    const int2* pk = pack + row_start[node];       // 32B-aligned (start % 4 == 0)
    const int cpad = (cnt[node] + 3) & ~3;
    for (int e = 0; e < cpad; e += 4) {
        const int4 a = *(const int4*)(pk + e);
        const int4 b = *(const int4*)(pk + e + 2);
        {
            const ushort4_t v = *(const ushort4_t*)(h + (size_t)a.x * D + f);
            const float n = __int_as_float(a.y);
            acc.x += bf2f(v.x) * n; acc.y += bf2f(v.y) * n;
            acc.z += bf2f(v.z) * n; acc.w += bf2f(v.w) * n;
        }
        {
            const ushort4_t v = *(const ushort4_t*)(h + (size_t)a.z * D + f);
            const float n = __int_as_float(a.w);
            acc.x += bf2f(v.x) * n; acc.y += bf2f(v.y) * n;
            acc.z += bf2f(v.z) * n; acc.w += bf2f(v.w) * n;
        }
        {
            const ushort4_t v = *(const ushort4_t*)(h + (size_t)b.x * D + f);
            const float n = __int_as_float(b.y);
            acc.x += bf2f(v.x) * n; acc.y += bf2f(v.y) * n;
            acc.z += bf2f(v.z) * n; acc.w += bf2f(v.w) * n;
        }
        {
            const ushort4_t v = *(const ushort4_t*)(h + (size_t)b.z * D + f);
            const float n = __int_as_float(b.w);
            acc.x += bf2f(v.x) * n; acc.y += bf2f(v.y) * n;
            acc.z += bf2f(v.z) * n; acc.w += bf2f(v.w) * n;
        }
    }
    if (RELU) {
        acc.x = fmaxf(acc.x, 0.f); acc.y = fmaxf(acc.y, 0.f);
        acc.z = fmaxf(acc.z, 0.f); acc.w = fmaxf(acc.w, 0.f);
    }
    if (BF16_OUT) {
        unsigned int* out = (unsigned int*)outv;
        uint2 pv;
        pv.x = pack2(acc.x, acc.y);
        pv.y = pack2(acc.z, acc.w);
        *(uint2*)(out + ((size_t)node * D + f) / 2) = pv;
    } else {
        float* out = (float*)outv;
        *(float4*)(out + (size_t)node * D + f) = acc;
    }
}

extern "C" void kernel_launch(void* const* d_in, const int* in_sizes, int n_in,
                              void* d_out, int out_size, void* d_ws, size_t ws_size,
                              hipStream_t stream) {
    const float* x   = (const float*)d_in[0];
    const int*   ei  = (const int*)  d_in[1];
    const float* W1  = (const float*)d_in[2];
    const float* b1  = (const float*)d_in[3];
    const float* W2  = (const float*)d_in[4];
    const float* b2  = (const float*)d_in[5];
    float* out = (float*)d_out;

    const int N = in_sizes[0] / IN_DIM;     // 100000
    const int E = in_sizes[1] / 2;          // 1600000
    const int* src = ei;                    // edge_index[0]
    const int* dst = ei + E;                // edge_index[1]

    // workspace layout (4B units):
    // dinv[N] | cnt[N] | row_start[N] | bbase[NBUK+1] | bcnt[NBUK] | mat[NB1*NBUK]
    // | align16 | pack[E+4N] int2 | h1[N*64] u32 | agg1[N*64] u32 (ebuf[E] int2 aliases agg1)
    const int PACK_CAP = E + 4 * N;
    float* dinv      = (float*)d_ws;
    int*   cnt       = (int*)(dinv + N);
    int*   row_start = cnt + N;
    int*   bbase     = row_start + N;
    int*   bcnt      = bbase + (NBUK + 1);
    int*   mat       = bcnt + NBUK;
    size_t off       = (size_t)(3 * N) + (NBUK + 1) + NBUK + (size_t)NB1 * NBUK;
    off = (off + 3) & ~(size_t)3;           // 16B-align pack
    int2*  pack      = (int2*)((int*)d_ws + off);
    unsigned int* h1 = (unsigned int*)(pack + PACK_CAP);
    unsigned int* agg1 = h1 + (size_t)N * (HID_DIM / 2);
    int2*  ebuf      = (int2*)agg1;         // E*8B <= N*256B; dead before gather128 writes agg1
    unsigned int* h2 = h1;                  // reuse after gather128

    const int S   = (N + 2047) / 2048;      // scan blocks
    const int NT  = (N + 15) / 16;          // 16-node MFMA tiles
    const int NBK = (N + 127) >> 7;         // active buckets (782)
    const int CH  = (E + NB1 - 1) / NB1;    // edges per hist/scatter block

    // 1) h1 = x @ W1 (standalone; atomic count phase eliminated)
    gemm1_mfma<<<1568, 256, 0, stream>>>(x, W1, h1, N, NT, 1568 * 4);

    // 2) bucket CSR build: hist -> matrix scan -> scatter -> per-bucket count
    bucket_hist<<<NB1, 256, 0, stream>>>(dst, E, CH, mat);
    mat_scan<<<1, 1024, 0, stream>>>(mat, bbase, bcnt);
    bucket_scatter<<<NB1, 256, 0, stream>>>(src, dst, E, CH, mat, ebuf);
    bucket_count<<<NBK, 256, 0, stream>>>(ebuf, bbase, bcnt, cnt, N);

    // 3) dinv + row_start (single launch)
    scan_fused<<<S, 256, 0, stream>>>(cnt, dinv, row_start, N);

    // 4) per-bucket record build in LDS, coalesced flush (pads included)
    bucket_build<<<NBK, 256, 0, stream>>>(ebuf, bbase, bcnt, row_start, cnt, dinv, N, pack);

    // 5) agg1 = relu(gather(h1) + b1)  (bf16 out; overwrites ebuf)
    gather_bf16<HID_DIM, true, true><<<(N + 7) / 8, 256, 0, stream>>>(
        (const ushort_t*)h1, pack, row_start, cnt, dinv, b1, N, (void*)agg1);

    // 6) h2 = agg1 @ W2  (bf16 out, MFMA, raw b-frag loads)
    gemm2_mfma<<<768, 256, 0, stream>>>(
        (const ushort_t*)agg1, W2, h2, N, NT, 768 * 4);

    // 7) out = b2 + gather(h2)  (f32 out)
    gather_bf16<OUT_DIM, false, false><<<(N + 15) / 16, 256, 0, stream>>>(
        (const ushort_t*)h2, pack, row_start, cnt, dinv, b2, N, (void*)out);
}

// Round 11
// 313.429 us; speedup vs baseline: 1.3149x; 1.3149x over previous
//
#include <hip/hip_runtime.h>
#include <hip/hip_bf16.h>

#define IN_DIM  128
#define HID_DIM 128
#define OUT_DIM 64

typedef unsigned short ushort_t;
struct ushort4_t { ushort_t x, y, z, w; };
struct __align__(16) ushort8_t { ushort_t u[8]; };
typedef __attribute__((ext_vector_type(8))) short bf16x8;   // 8 bf16 (4 VGPRs)
typedef __attribute__((ext_vector_type(4))) float f32x4;    // MFMA acc

__device__ __forceinline__ float bf2f(ushort_t u) {
    return __uint_as_float(((unsigned int)u) << 16);
}
__device__ __forceinline__ short f2bf_s(float v) {
    __hip_bfloat16 t = __float2bfloat16(v);
    return *(short*)&t;
}
__device__ __forceinline__ unsigned int pack2(float a, float b) {
    return ((unsigned int)(ushort_t)f2bf_s(b) << 16) | (ushort_t)f2bf_s(a);
}

// ---------------- FUSED: gemm1 (odd blocks) || count+rank (even blocks) ----------------
// count role is device-atomic-throughput-bound (~24G line-RMW/s HW ceiling: insensitive to
// grid [r0/r1], collisions [r6], depth [r8], buckets [r10]) and hides the whole GEMM for free.
__global__ __launch_bounds__(256, 2) void fused_gemm1_count(
        const float* __restrict__ x, const float* __restrict__ W,
        unsigned int* __restrict__ h,
        const int* __restrict__ dst, int* __restrict__ cnt, int* __restrict__ rank,
        int N, int E, int NT) {
    const int bid = blockIdx.x;
    const int tid = threadIdx.x;

    if (bid & 1) {
        // ---- GEMM1 role ----
        const int lane = tid & 63;
        const int m    = lane & 15;
        const int quad = lane >> 4;
        const int gw   = (bid >> 1) * 4 + (tid >> 6);
        const int NW   = 1024;                  // 256 blocks x 4 waves

        bf16x8 a[8][4];                         // 8 col-tiles x 4 k-chunks
        #pragma unroll
        for (int ct = 0; ct < 8; ++ct)
            #pragma unroll
            for (int kc = 0; kc < 4; ++kc)
                #pragma unroll
                for (int j = 0; j < 8; ++j)
                    a[ct][kc][j] = f2bf_s(W[(size_t)(kc * 32 + quad * 8 + j) * HID_DIM + ct * 16 + m]);

        for (int t = gw; t < NT; t += NW) {
            const int n0 = t * 16;
            int node = n0 + m; if (node >= N) node = N - 1;
            const float* xr = x + (size_t)node * IN_DIM + quad * 8;
            f32x4 acc[8];
            #pragma unroll
            for (int ct = 0; ct < 8; ++ct) acc[ct] = (f32x4){0.f, 0.f, 0.f, 0.f};
            #pragma unroll
            for (int kc = 0; kc < 4; ++kc) {
                const float4 v0 = *(const float4*)(xr + kc * 32);
                const float4 v1 = *(const float4*)(xr + kc * 32 + 4);
                bf16x8 b;
                b[0] = f2bf_s(v0.x); b[1] = f2bf_s(v0.y); b[2] = f2bf_s(v0.z); b[3] = f2bf_s(v0.w);
                b[4] = f2bf_s(v1.x); b[5] = f2bf_s(v1.y); b[6] = f2bf_s(v1.z); b[7] = f2bf_s(v1.w);
                #pragma unroll
                for (int ct = 0; ct < 8; ++ct)
                    acc[ct] = __builtin_amdgcn_mfma_f32_16x16x32_bf16(a[ct][kc], b, acc[ct], 0, 0, 0);
            }
            if (n0 + m < N) {
                unsigned int* o = h + (size_t)(n0 + m) * (HID_DIM / 2) + quad * 2;
                #pragma unroll
                for (int ct = 0; ct < 8; ++ct) {
                    uint2 pv;
                    pv.x = pack2(acc[ct][0], acc[ct][1]);
                    pv.y = pack2(acc[ct][2], acc[ct][3]);
                    *(uint2*)(o + ct * 8) = pv;
                }
            }
        }
    } else {
        // ---- count + rank role ----
        const int ct = (bid >> 1) * 256 + tid;
        const int CT = 256 * 256;
        const int nq = E >> 2;
        const int4* d4 = (const int4*)dst;
        for (int q = ct; q < nq; q += CT) {
            const int4 d = d4[q];
            int4 r;
            r.x = atomicAdd(&cnt[d.x], 1);
            r.y = atomicAdd(&cnt[d.y], 1);
            r.z = atomicAdd(&cnt[d.z], 1);
            r.w = atomicAdd(&cnt[d.w], 1);
            ((int4*)rank)[q] = r;
        }
        for (int e = (nq << 2) + ct; e < E; e += CT)
            rank[e] = atomicAdd(&cnt[dst[e]], 1);
    }
}

// ---------------- scan_fused: dinv + row_start + {0,0} pad records, ONE launch ----------------
// Each block re-derives its global offset by summing all preceding padded counts directly.
__global__ void scan_fused(const int* __restrict__ cnt, float* __restrict__ dinv,
                           int* __restrict__ row_start, int2* __restrict__ pack, int N) {
    __shared__ int wsum[4];
    __shared__ int sh_off;
    const int t = threadIdx.x;
    const int base0 = blockIdx.x * 2048;

    int pre = 0;
    for (int i = t * 4; i < base0; i += 1024) {
        const int4 c4 = *(const int4*)(cnt + i);
        pre += ((c4.x + 3) & ~3) + ((c4.y + 3) & ~3) + ((c4.z + 3) & ~3) + ((c4.w + 3) & ~3);
    }
    #pragma unroll
    for (int off = 32; off > 0; off >>= 1) pre += __shfl_down(pre, off);
    const int lane = t & 63, w = t >> 6;
    if (lane == 0) wsum[w] = pre;
    __syncthreads();
    if (t == 0) sh_off = wsum[0] + wsum[1] + wsum[2] + wsum[3];
    __syncthreads();

    const int base = base0 + t * 8;
    int c[8], v[8];
    #pragma unroll
    for (int i = 0; i < 8; ++i) {
        c[i] = (base + i < N) ? cnt[base + i] : 0;
        v[i] = (c[i] + 3) & ~3;
        if (base + i < N) dinv[base + i] = rsqrtf((float)(c[i] + 1));   // +1 self loop
    }
    int s = v[0] + v[1] + v[2] + v[3] + v[4] + v[5] + v[6] + v[7];
    int incl = s;
    #pragma unroll
    for (int off = 1; off < 64; off <<= 1) {
        int u = __shfl_up(incl, off);
        if (lane >= off) incl += u;
    }
    if (lane == 63) wsum[w] = incl;
    __syncthreads();
    int woff = 0;
    for (int i = 0; i < w; ++i) woff += wsum[i];
    int run = sh_off + woff + (incl - s);
    const int2 zr = {0, 0};
    #pragma unroll
    for (int i = 0; i < 8; ++i) {
        if (base + i < N) {
            row_start[base + i] = run;
            for (int p = c[i]; p < v[i]; ++p) pack[run + p] = zr;   // pad: src=0, norm=0
            run += v[i];
        }
    }
}

// ---------------- fill packed CSR records {src, norm} (8B), no atomics, x4-vectorized ----------------
__global__ void fill_pack4(const int* __restrict__ src, const int* __restrict__ dst,
                           const int* __restrict__ rank, const int* __restrict__ row_start,
                           const float* __restrict__ dinv, int E, int2* __restrict__ pack) {
    const int q = blockIdx.x * blockDim.x + threadIdx.x;
    const int nq = E >> 2;
    if (q < nq) {
        const int4 s = ((const int4*)src)[q];
        const int4 d = ((const int4*)dst)[q];
        const int4 r = ((const int4*)rank)[q];
        int2 p;
        p.x = s.x; p.y = __float_as_int(dinv[s.x] * dinv[d.x]);
        pack[row_start[d.x] + r.x] = p;
        p.x = s.y; p.y = __float_as_int(dinv[s.y] * dinv[d.y]);
        pack[row_start[d.y] + r.y] = p;
        p.x = s.z; p.y = __float_as_int(dinv[s.z] * dinv[d.z]);
        pack[row_start[d.z] + r.z] = p;
        p.x = s.w; p.y = __float_as_int(dinv[s.w] * dinv[d.w]);
        pack[row_start[d.w] + r.w] = p;
    }
    if (q == 0) {   // tail (E not multiple of 4)
        for (int e = nq << 2; e < E; ++e) {
            int2 p;
            p.x = src[e]; p.y = __float_as_int(dinv[src[e]] * dinv[dst[e]]);
            pack[row_start[dst[e]] + rank[e]] = p;
        }
    }
}

// ---------------- FUSED gather128 + gemm2: h2 = relu(gather(h1)+b1) @ W2, no agg1 round-trip ----------------
// Block = 16 nodes. Phase A: 16 threads/node x 8 dims gather -> bias+relu -> bf16 LDS tile.
// Phase B: 4 waves, each one 16x16 MFMA col-tile of the 16-node x 64-col output.
__global__ __launch_bounds__(256) void gather128_gemm2(
        const ushort_t* __restrict__ h, const int2* __restrict__ pack,
        const int* __restrict__ row_start, const int* __restrict__ cnt,
        const float* __restrict__ dinv, const float* __restrict__ b1,
        const float* __restrict__ W2, unsigned int* __restrict__ h2,
        int N, int NT2, int NBLK) {
    __shared__ ushort_t tile[16][136];      // stride 136 shorts = 272B (16B-mult, bank-spread)
    const int tid  = threadIdx.x;
    const int lane = tid & 63;
    const int wid  = tid >> 6;              // wave id = output col-tile ct
    const int m    = lane & 15;
    const int quad = lane >> 4;

    bf16x8 a[4];                            // W2 col-tile for this wave, loaded once
    #pragma unroll
    for (int kc = 0; kc < 4; ++kc)
        #pragma unroll
        for (int j = 0; j < 8; ++j)
            a[kc][j] = f2bf_s(W2[(size_t)(kc * 32 + quad * 8 + j) * OUT_DIM + wid * 16 + m]);

    const int gn = tid >> 4;                // node slot 0..15 (gather phase)
    const int f0 = (tid & 15) * 8;          // dim base (8 dims/thread)

    for (int t = blockIdx.x; t < NT2; t += NBLK) {
        const int n0 = t * 16;
        int node = n0 + gn; if (node >= N) node = N - 1;
        const float dd = dinv[node];
        float accv[8];
        {   // self term + bias
            const float sn = dd * dd;
            const ushort8_t hv = *(const ushort8_t*)(h + (size_t)node * HID_DIM + f0);
            #pragma unroll
            for (int i = 0; i < 8; ++i) accv[i] = bf2f(hv.u[i]) * sn + b1[f0 + i];
        }
        const int2* pk = pack + row_start[node];
        const int cpad = (cnt[node] + 3) & ~3;
        for (int e = 0; e < cpad; e += 4) {
            const int4 pa = *(const int4*)(pk + e);
            const int4 pb = *(const int4*)(pk + e + 2);
            {
                const ushort8_t v = *(const ushort8_t*)(h + (size_t)pa.x * HID_DIM + f0);
                const float n = __int_as_float(pa.y);
                #pragma unroll
                for (int i = 0; i < 8; ++i) accv[i] += bf2f(v.u[i]) * n;
            }
            {
                const ushort8_t v = *(const ushort8_t*)(h + (size_t)pa.z * HID_DIM + f0);
                const float n = __int_as_float(pa.w);
                #pragma unroll
                for (int i = 0; i < 8; ++i) accv[i] += bf2f(v.u[i]) * n;
            }
            {
                const ushort8_t v = *(const ushort8_t*)(h + (size_t)pb.x * HID_DIM + f0);
                const float n = __int_as_float(pb.y);
                #pragma unroll
                for (int i = 0; i < 8; ++i) accv[i] += bf2f(v.u[i]) * n;
            }
            {
                const ushort8_t v = *(const ushort8_t*)(h + (size_t)pb.z * HID_DIM + f0);
                const float n = __int_as_float(pb.w);
                #pragma unroll
                for (int i = 0; i < 8; ++i) accv[i] += bf2f(v.u[i]) * n;
            }
        }
        ushort8_t pv;                       // relu -> bf16, one 16B LDS store
        #pragma unroll
        for (int i = 0; i < 8; ++i) pv.u[i] = (ushort_t)f2bf_s(fmaxf(accv[i], 0.f));
        *(ushort8_t*)&tile[gn][f0] = pv;
        __syncthreads();

        // Phase B: MFMA. B[k][n=m] from LDS row m; A = W2 col-tile wid.
        f32x4 acc = (f32x4){0.f, 0.f, 0.f, 0.f};
        #pragma unroll
        for (int kc = 0; kc < 4; ++kc) {
            const bf16x8 b = *(const bf16x8*)&tile[m][kc * 32 + quad * 8];
            acc = __builtin_amdgcn_mfma_f32_16x16x32_bf16(a[kc], b, acc, 0, 0, 0);
        }
        if (n0 + m < N) {
            unsigned int* o = h2 + (size_t)(n0 + m) * (OUT_DIM / 2) + wid * 8 + quad * 2;
            uint2 ov;
            ov.x = pack2(acc[0], acc[1]);
            ov.y = pack2(acc[2], acc[3]);
            *(uint2*)o = ov;
        }
        __syncthreads();                    // protect tile before next iteration's writes
    }
}

// ---------------- gather aggregation over {src, norm} records (round-4 verified form) ----------------
template<int D, bool BF16_OUT, bool RELU>
__global__ void gather_bf16(const ushort_t* __restrict__ h, const int2* __restrict__ pack,
                            const int* __restrict__ row_start, const int* __restrict__ cnt,
                            const float* __restrict__ dinv, const float* __restrict__ bias,
                            int N, void* __restrict__ outv) {
    const int TPN = D / 4;
    const int NPB = 256 / TPN;
    const int t = threadIdx.x;
    const int node = blockIdx.x * NPB + t / TPN;
    if (node >= N) return;
    const int f = (t & (TPN - 1)) * 4;
    const float dd = dinv[node];

    const ushort4_t self = *(const ushort4_t*)(h + (size_t)node * D + f);
    const float sn = dd * dd;
    float4 acc;
    acc.x = bf2f(self.x) * sn; acc.y = bf2f(self.y) * sn;
    acc.z = bf2f(self.z) * sn; acc.w = bf2f(self.w) * sn;
    const float4 bv = *(const float4*)(bias + f);
    acc.x += bv.x; acc.y += bv.y; acc.z += bv.z; acc.w += bv.w;

    const int2* pk = pack + row_start[node];       // 32B-aligned (start % 4 == 0)
    const int cpad = (cnt[node] + 3) & ~3;
    for (int e = 0; e < cpad; e += 4) {
        const int4 a = *(const int4*)(pk + e);
        const int4 b = *(const int4*)(pk + e + 2);
        {
            const ushort4_t v = *(const ushort4_t*)(h + (size_t)a.x * D + f);
            const float n = __int_as_float(a.y);
            acc.x += bf2f(v.x) * n; acc.y += bf2f(v.y) * n;
            acc.z += bf2f(v.z) * n; acc.w += bf2f(v.w) * n;
        }
        {
            const ushort4_t v = *(const ushort4_t*)(h + (size_t)a.z * D + f);
            const float n = __int_as_float(a.w);
            acc.x += bf2f(v.x) * n; acc.y += bf2f(v.y) * n;
            acc.z += bf2f(v.z) * n; acc.w += bf2f(v.w) * n;
        }
        {
            const ushort4_t v = *(const ushort4_t*)(h + (size_t)b.x * D + f);
            const float n = __int_as_float(b.y);
            acc.x += bf2f(v.x) * n; acc.y += bf2f(v.y) * n;
            acc.z += bf2f(v.z) * n; acc.w += bf2f(v.w) * n;
        }
        {
            const ushort4_t v = *(const ushort4_t*)(h + (size_t)b.z * D + f);
            const float n = __int_as_float(b.w);
            acc.x += bf2f(v.x) * n; acc.y += bf2f(v.y) * n;
            acc.z += bf2f(v.z) * n; acc.w += bf2f(v.w) * n;
        }
    }
    if (RELU) {
        acc.x = fmaxf(acc.x, 0.f); acc.y = fmaxf(acc.y, 0.f);
        acc.z = fmaxf(acc.z, 0.f); acc.w = fmaxf(acc.w, 0.f);
    }
    if (BF16_OUT) {
        unsigned int* out = (unsigned int*)outv;
        uint2 pv;
        pv.x = pack2(acc.x, acc.y);
        pv.y = pack2(acc.z, acc.w);
        *(uint2*)(out + ((size_t)node * D + f) / 2) = pv;
    } else {
        float* out = (float*)outv;
        *(float4*)(out + (size_t)node * D + f) = acc;
    }
}

extern "C" void kernel_launch(void* const* d_in, const int* in_sizes, int n_in,
                              void* d_out, int out_size, void* d_ws, size_t ws_size,
                              hipStream_t stream) {
    const float* x   = (const float*)d_in[0];
    const int*   ei  = (const int*)  d_in[1];
    const float* W1  = (const float*)d_in[2];
    const float* b1  = (const float*)d_in[3];
    const float* W2  = (const float*)d_in[4];
    const float* b2  = (const float*)d_in[5];
    float* out = (float*)d_out;

    const int N = in_sizes[0] / IN_DIM;     // 100000
    const int E = in_sizes[1] / 2;          // 1600000
    const int* src = ei;                    // edge_index[0]
    const int* dst = ei + E;                // edge_index[1]

    // workspace layout (4B units):
    // dinv[N] | cnt[N] | row_start[N] | align | pack[E+4N] int2
    // | h1[N*64] u32 (bf16 h1, reused as h2) | rank[E] (aliases old agg1 slot)
    const int PACK_CAP = E + 4 * N;
    float* dinv      = (float*)d_ws;
    int*   cnt       = (int*)(dinv + N);
    int*   row_start = cnt + N;
    size_t off       = (size_t)(3 * N);
    off = (off + 3) & ~(size_t)3;           // 16B-align pack
    int2*  pack      = (int2*)((int*)d_ws + off);
    unsigned int* h1 = (unsigned int*)(pack + PACK_CAP);
    int*   rank      = (int*)(h1 + (size_t)N * (HID_DIM / 2));   // alive until fill_pack
    unsigned int* h2 = h1;                  // h2 overwrites h1 region (gather128_gemm2 reads
                                            // h1 rows randomly BUT writes h2 to same base...
    // SAFETY: h2 must NOT alias h1 (fused kernel reads h1 while writing h2) -> place h2 after rank.
    unsigned int* h2_safe = (unsigned int*)(rank + E);

    const int B = 256;
    const int S = (N + 2047) / 2048;        // scan blocks
    const int NT = (N + 15) / 16;           // 16-node MFMA tiles

    // 1) CSR counts + rank, fused with GEMM1 (independent work hides atomic throughput floor)
    hipMemsetAsync(cnt, 0, (size_t)N * sizeof(int), stream);
    fused_gemm1_count<<<512, 256, 0, stream>>>(x, W1, h1, dst, cnt, rank, N, E, NT);

    // 2) dinv + row_start + pad records (single launch)
    scan_fused<<<S, 256, 0, stream>>>(cnt, dinv, row_start, pack, N);

    // 3) fill packed CSR records {src, norm}
    fill_pack4<<<((E >> 2) + B - 1) / B, B, 0, stream>>>(src, dst, rank, row_start, dinv, E, pack);

    // 4) h2 = relu(gather(h1) + b1) @ W2  (fused: no agg1 round-trip, no gemm2 dispatch)
    gather128_gemm2<<<1024, 256, 0, stream>>>(
        (const ushort_t*)h1, pack, row_start, cnt, dinv, b1, W2, h2_safe, N, NT, 1024);

    // 5) out = b2 + gather(h2)  (f32 out)
    gather_bf16<OUT_DIM, false, false><<<(N + 15) / 16, 256, 0, stream>>>(
        (const ushort_t*)h2_safe, pack, row_start, cnt, dinv, b2, N, (void*)out);
}